// Round 4
// baseline (295.802 us; speedup 1.0000x reference)
//
#include <hip/hip_runtime.h>
#include <stdint.h>

typedef unsigned short ushortT;

#define NROWS 131072
#define DIM 64
#define KCODES 1024
// 5 segments (xplane,eplane) = (0,0),(0,1),(0,2),(1,0),(2,0); x1e1 dropped (~4e-6).
// 6 DISTINCT planes each side: A = {x0d0,x0d1,x1d0,x1d1,x2d0,x2d1},
// B = {e0d0,e0d1,e1d0,e1d1,e2d0,e2d1}. 10 MFMA clusters grouped by B-plane ->
// 6 B loads/ci (L2 traffic x0.6 vs R13). Cluster order verified R3 (absmax
// 1.953125e-3, no argmin flips).
#define NPL 6               // distinct planes per side
#define MT 64               // rows per block (256 threads, 4 waves)
#define NTC 256             // codes per code-iter (4 waves x 64)
#define CI (KCODES / NTC)   // 4 code iters
#define KCSTEP (4 * KCODES * 8)  // ushort per B plane = 32768 (64KB)
#define ASTEP (4 * MT * 8)       // ushort per A plane = 2048 (4KB)

typedef float f32x4 __attribute__((ext_vector_type(4)));
typedef short bf16x8 __attribute__((ext_vector_type(8)));

__device__ __forceinline__ ushortT f2bf(float f) {
  union { float f; uint32_t u; } v; v.f = f;
  return (ushortT)((v.u + 0x7FFFu + ((v.u >> 16) & 1u)) >> 16);  // RNE
}
__device__ __forceinline__ float bf2f(ushortT b) {
  union { float f; uint32_t u; } v; v.u = ((uint32_t)b) << 16;
  return v.f;
}

// Output-major prep (verified R3): flat o = p*32768 + q*8192 + code*8 + j;
// thread does 4 consecutive o (one uint2 store, coalesced). plane p: e-level
// ep = p>>1, d-half = p&1. h2[code] = 0.5*||e||^2 fp32 by blocks 0..3.
__global__ __launch_bounds__(256) void vq_prep(const float* __restrict__ emb,
                                               ushortT* __restrict__ Bg,
                                               float* __restrict__ h2) {
  const int o4 = (blockIdx.x * 256 + threadIdx.x) * 4;
  const int j0 = o4 & 7;                  // 0 or 4
  const int code = (o4 >> 3) & (KCODES - 1);
  const int q = (o4 >> 13) & 3;
  const int p = o4 >> 15;                 // 0..5 (block-uniform)
  const int ep = p >> 1;
  const int d0 = (p & 1) * 32 + q * 8 + j0;

  ushortT outv[4];
#pragma unroll
  for (int t = 0; t < 4; ++t) {
    float e = emb[(d0 + t) * KCODES + code];
    ushortT p0 = f2bf(e);
    ushortT pv = p0;
    if (ep == 1) {
      float r1 = e - bf2f(p0);            // exact (Sterbenz)
      pv = f2bf(r1);
    } else if (ep == 2) {
      float r1 = e - bf2f(p0);
      ushortT p1 = f2bf(r1);
      float r2 = r1 - bf2f(p1);           // exact
      pv = f2bf(r2);
    }
    outv[t] = pv;
  }
  *(uint2*)(&Bg[o4]) = *(const uint2*)(&outv[0]);

  if (blockIdx.x < 4) {
    const int c2 = blockIdx.x * 256 + threadIdx.x;
    float s = 0.f;
#pragma unroll
    for (int d = 0; d < DIM; ++d) {
      float e = emb[d * KCODES + c2];
      s = fmaf(e, e, s);
    }
    h2[c2] = 0.5f * s;
  }
}

// R17: R13 skeleton (verified 121us, no spill: back-edge live set = bestv/besti
// + pointers only) + plane-dedup (6 B loads/ci). NO cross-ci carried vector
// state — R2/R3 both spilled ~360B/thread (WRITE_SIZE 217MB vs 32MB) from
// loop-carried b-ring/a-prefetch across the ci back-edge. Per-ci: preload
// 3-slot B ring (p0,p1,p2), a[0]<-plane0 from LDS, then 10 clusters:
//   c0-2: s0=p0 x a{0,2,4}; reload s0<-p3 after c2 (use c7, dist 4)
//   c3-5: s1=p1 x a{1,3,5}; reload s1<-p4 after c5 (use c8, dist 2)
//   c6:   s2=p2 x a0;       reload s2<-p5 after c6 (use c9, dist 2)
//   c7-9: p3 x a1, p4 x a0, p5 x a1
// Restart cost ~200cy/ci exposed (~3%/block). Macro w/ literal args: all
// indexing compile-time (rule-#20 proof).
__global__ __launch_bounds__(256, 3) void vq_main(const float* __restrict__ x,
                                                  const ushortT* __restrict__ Bg,
                                                  const float* __restrict__ h2,
                                                  const float* __restrict__ emb,
                                                  float* __restrict__ out) {
  __shared__ ushortT A_lds[NPL * ASTEP];  // 24 KB  [plane][quad][row][8]
  __shared__ float bvs[4][MT];
  __shared__ int bis[4][MT];
  __shared__ int widx_s[MT];

  const int tid = threadIdx.x;
  const int wave = tid >> 6, lane = tid & 63, quad = lane >> 4, lq = lane & 15;
  const size_t rowbase = (size_t)blockIdx.x * MT;

  const ushortT* bci = Bg + ((size_t)(quad * KCODES + wave * 64 + lq)) * 8;
  const ushortT* ab = &A_lds[quad * (MT * 8) + lq * 8];

  // ---- stage A: x rows -> bf16 planes, frag-major, dedup'd (6 planes) ----
  {
    const int row = tid >> 2, dg = (tid & 3) << 4;
    const float4* xr = (const float4*)(x + (rowbase + row) * DIM + dg);
    float v[16];
#pragma unroll
    for (int i = 0; i < 4; ++i) {
      float4 t = xr[i];
      v[4 * i] = t.x; v[4 * i + 1] = t.y; v[4 * i + 2] = t.z; v[4 * i + 3] = t.w;
    }
    ushortT pl[3][16];
#pragma unroll
    for (int i = 0; i < 16; ++i) {
      ushortT a0 = f2bf(v[i]); float r1 = v[i] - bf2f(a0);
      ushortT a1 = f2bf(r1);   float r2 = r1 - bf2f(a1);
      pl[0][i] = a0; pl[1][i] = a1; pl[2][i] = f2bf(r2);
    }
    const int q0 = (dg & 31) >> 3;         // 0 or 2
    const int dh = dg >> 5;                // d-half
#pragma unroll
    for (int xp = 0; xp < 3; ++xp) {
      int pa = xp * 2 + dh;
      *(uint4*)&A_lds[pa * ASTEP + q0 * (MT * 8) + row * 8]       = *(uint4*)&pl[xp][0];
      *(uint4*)&A_lds[pa * ASTEP + (q0 + 1) * (MT * 8) + row * 8] = *(uint4*)&pl[xp][8];
    }
  }
  __syncthreads();  // A_lds ready; only block-wide barrier before epilogue

  float bestv[4][4];
  int besti[4][4];
#pragma unroll
  for (int i = 0; i < 4; ++i)
#pragma unroll
    for (int r = 0; r < 4; ++r) { bestv[i][r] = 3.4e38f; besti[i][r] = 0; }

// cluster macro: PC/PN = a ping-pong cur/next, APN = a-plane to prefetch
// (-1 none), S = b slot, DO_RL/RS/RP = b ring reload. All args literal.
#define CLUSTER(PC, PN, APN, S, DO_RL, RS, RP)                                 \
  {                                                                            \
    if ((APN) >= 0) {                                                          \
      _Pragma("unroll")                                                        \
      for (int i = 0; i < 4; ++i)                                              \
        a[PN][i] = *(const bf16x8*)(ab + (size_t)(APN < 0 ? 0 : APN) * ASTEP + i * 128); \
    }                                                                          \
    _Pragma("unroll")                                                          \
    for (int i = 0; i < 4; ++i)                                                \
      _Pragma("unroll")                                                        \
      for (int j = 0; j < 4; ++j)                                              \
        acc[i][j] = __builtin_amdgcn_mfma_f32_16x16x32_bf16(a[PC][i], b[S][j], \
                                                            acc[i][j], 0, 0, 0); \
    if (DO_RL) {                                                               \
      _Pragma("unroll")                                                        \
      for (int j = 0; j < 4; ++j)                                              \
        b[RS][j] = *(const bf16x8*)(bcur + (size_t)(RP) * KCSTEP + j * 128);   \
    }                                                                          \
  }

#pragma unroll 1
  for (int ci = 0; ci < CI; ++ci) {
    const int codeBase = ci * NTC;
    const ushortT* bcur = bci + (size_t)codeBase * 8;

    bf16x8 a[2][4], b[3][4];
    // preload B ring: s0<-p0 (e0d0), s1<-p1 (e0d1), s2<-p2 (e1d0)
#pragma unroll
    for (int s = 0; s < 3; ++s)
#pragma unroll
      for (int j = 0; j < 4; ++j)
        b[s][j] = *(const bf16x8*)(bcur + (size_t)s * KCSTEP + j * 128);
    // a[0] <- plane 0 (x0d0)
#pragma unroll
    for (int i = 0; i < 4; ++i) a[0][i] = *(const bf16x8*)(ab + i * 128);

    f32x4 acc[4][4];
#pragma unroll
    for (int i = 0; i < 4; ++i)
#pragma unroll
      for (int j = 0; j < 4; ++j) acc[i][j] = (f32x4){0.f, 0.f, 0.f, 0.f};

    CLUSTER(0, 1, 2, 0, 0, 0, 0)   // c0: a(p0) x s0(p0); pre a<-p2
    CLUSTER(1, 0, 4, 0, 0, 0, 0)   // c1: a(p2) x s0;     pre a<-p4
    CLUSTER(0, 1, 1, 0, 1, 0, 3)   // c2: a(p4) x s0;     pre a<-p1; s0<-p3
    CLUSTER(1, 0, 3, 1, 0, 0, 0)   // c3: a(p1) x s1(p1); pre a<-p3
    CLUSTER(0, 1, 5, 1, 0, 0, 0)   // c4: a(p3) x s1;     pre a<-p5
    CLUSTER(1, 0, 0, 1, 1, 1, 4)   // c5: a(p5) x s1;     pre a<-p0; s1<-p4
    CLUSTER(0, 1, 1, 2, 1, 2, 5)   // c6: a(p0) x s2(p2); pre a<-p1; s2<-p5
    CLUSTER(1, 0, 0, 0, 0, 0, 0)   // c7: a(p1) x s0(p3); pre a<-p0
    CLUSTER(0, 1, 1, 1, 0, 0, 0)   // c8: a(p0) x s1(p4); pre a<-p1
    CLUSTER(1, 0, -1, 2, 0, 0, 0)  // c9: a(p1) x s2(p5)

    // epilogue: val = 0.5||e||^2 - f.e ; merge into per-row running best
    float h2v[4];
#pragma unroll
    for (int j = 0; j < 4; ++j) h2v[j] = h2[codeBase + wave * 64 + j * 16 + lq];
#pragma unroll
    for (int i = 0; i < 4; ++i)
#pragma unroll
      for (int j = 0; j < 4; ++j) {
        const int idx = codeBase + wave * 64 + j * 16 + lq;
#pragma unroll
        for (int r = 0; r < 4; ++r) {
          float val = h2v[j] - acc[i][j][r];
          if (val < bestv[i][r]) { bestv[i][r] = val; besti[i][r] = idx; }  // idx ascending in (ci,j): strict < keeps lowest
        }
      }
  }
#undef CLUSTER

  // reduce across the 16 lanes sharing a quad (lane bits 0-3), lexicographic (val, idx)
#pragma unroll
  for (int m = 1; m < 16; m <<= 1) {
#pragma unroll
    for (int i = 0; i < 4; ++i)
#pragma unroll
      for (int r = 0; r < 4; ++r) {
        float ov = __shfl_xor(bestv[i][r], m, 64);
        int oi = __shfl_xor(besti[i][r], m, 64);
        if (ov < bestv[i][r] || (ov == bestv[i][r] && oi < besti[i][r])) {
          bestv[i][r] = ov; besti[i][r] = oi;
        }
      }
  }
  if (lq == 0) {
#pragma unroll
    for (int i = 0; i < 4; ++i)
#pragma unroll
      for (int r = 0; r < 4; ++r) {
        int row = i * 16 + quad * 4 + r;
        bvs[wave][row] = bestv[i][r];
        bis[wave][row] = besti[i][r];
      }
  }
  __syncthreads();
  if (tid < MT) {
    float bv = bvs[0][tid]; int bi = bis[0][tid];
#pragma unroll
    for (int w = 1; w < 4; ++w) {
      float ov = bvs[w][tid]; int oi = bis[w][tid];
      if (ov < bv || (ov == bv && oi < bi)) { bv = ov; bi = oi; }
    }
    widx_s[tid] = bi;
  }
  __syncthreads();
  // cooperative gather: thread handles row=tid>>2, 16 d's; emb is L2-resident (256KB)
  {
    const int row = tid >> 2, dg = (tid & 3) << 4;
    const int wi = widx_s[row];
    float4* o = (float4*)(out + (rowbase + row) * DIM + dg);
#pragma unroll
    for (int i = 0; i < 4; ++i) {
      float4 t;
      t.x = emb[(dg + 4 * i + 0) * KCODES + wi];
      t.y = emb[(dg + 4 * i + 1) * KCODES + wi];
      t.z = emb[(dg + 4 * i + 2) * KCODES + wi];
      t.w = emb[(dg + 4 * i + 3) * KCODES + wi];
      o[i] = t;
    }
  }
}

extern "C" void kernel_launch(void* const* d_in, const int* in_sizes, int n_in,
                              void* d_out, int out_size, void* d_ws, size_t ws_size,
                              hipStream_t stream) {
  const float* x = (const float*)d_in[0];
  const float* emb = (const float*)d_in[1];
  float* out = (float*)d_out;

  ushortT* Bg = (ushortT*)d_ws;               // 6*32768 ushort = 384 KB
  float* h2 = (float*)(Bg + NPL * (size_t)KCSTEP);  // 4 KB

  vq_prep<<<(NPL * KCSTEP) / (4 * 256), 256, 0, stream>>>(emb, Bg, h2);
  vq_main<<<NROWS / MT, 256, 0, stream>>>(x, Bg, h2, emb, out);
}

// Round 5
// 294.289 us; speedup vs baseline: 1.0051x; 1.0051x over previous
//
#include <hip/hip_runtime.h>
#include <stdint.h>

typedef unsigned short ushortT;

#define NROWS 131072
#define DIM 64
#define KCODES 1024
// 5 segments (xplane,eplane) = (0,0),(0,1),(0,2),(1,0),(2,0); x1e1 dropped (~4e-6).
// 6 DISTINCT planes each side: A = {x0d0,x0d1,x1d0,x1d1,x2d0,x2d1},
// B = {e0d0,e0d1,e1d0,e1d1,e2d0,e2d1}. 10 MFMA clusters grouped by B-plane ->
// 6 B loads/ci (was 12 incl. waste). Cluster order verified R3/R4 (absmax
// 1.953125e-3, no argmin flips).
// R18 SPILL LESSON (R2/R3/R4): ANY 3rd b slot spills ~360B/thread
// (WRITE_SIZE 217MB vs 32MB) regardless of structure. Register shape must
// stay EXACTLY a[2][4] + b[2][4] (R13's proven-spill-free shape, VGPR 72).
#define NPL 6               // distinct planes per side
#define MT 64               // rows per block (256 threads, 4 waves)
#define NTC 256             // codes per code-iter (4 waves x 64)
#define CI (KCODES / NTC)   // 4 code iters
#define KCSTEP (4 * KCODES * 8)  // ushort per B plane = 32768 (64KB)
#define ASTEP (4 * MT * 8)       // ushort per A plane = 2048 (4KB)

typedef float f32x4 __attribute__((ext_vector_type(4)));
typedef short bf16x8 __attribute__((ext_vector_type(8)));

__device__ __forceinline__ ushortT f2bf(float f) {
  union { float f; uint32_t u; } v; v.f = f;
  return (ushortT)((v.u + 0x7FFFu + ((v.u >> 16) & 1u)) >> 16);  // RNE
}
__device__ __forceinline__ float bf2f(ushortT b) {
  union { float f; uint32_t u; } v; v.u = ((uint32_t)b) << 16;
  return v.f;
}

// Output-major prep (verified R3/R4): flat o = p*32768 + q*8192 + code*8 + j;
// thread does 4 consecutive o (one uint2 store, coalesced). plane p: e-level
// ep = p>>1, d-half = p&1. h2[code] = 0.5*||e||^2 fp32 by blocks 0..3.
__global__ __launch_bounds__(256) void vq_prep(const float* __restrict__ emb,
                                               ushortT* __restrict__ Bg,
                                               float* __restrict__ h2) {
  const int o4 = (blockIdx.x * 256 + threadIdx.x) * 4;
  const int j0 = o4 & 7;                  // 0 or 4
  const int code = (o4 >> 3) & (KCODES - 1);
  const int q = (o4 >> 13) & 3;
  const int p = o4 >> 15;                 // 0..5 (block-uniform)
  const int ep = p >> 1;
  const int d0 = (p & 1) * 32 + q * 8 + j0;

  ushortT outv[4];
#pragma unroll
  for (int t = 0; t < 4; ++t) {
    float e = emb[(d0 + t) * KCODES + code];
    ushortT p0 = f2bf(e);
    ushortT pv = p0;
    if (ep == 1) {
      float r1 = e - bf2f(p0);            // exact (Sterbenz)
      pv = f2bf(r1);
    } else if (ep == 2) {
      float r1 = e - bf2f(p0);
      ushortT p1 = f2bf(r1);
      float r2 = r1 - bf2f(p1);           // exact
      pv = f2bf(r2);
    }
    outv[t] = pv;
  }
  *(uint2*)(&Bg[o4]) = *(const uint2*)(&outv[0]);

  if (blockIdx.x < 4) {
    const int c2 = blockIdx.x * 256 + threadIdx.x;
    float s = 0.f;
#pragma unroll
    for (int d = 0; d < DIM; ++d) {
      float e = emb[d * KCODES + c2];
      s = fmaf(e, e, s);
    }
    h2[c2] = 0.5f * s;
  }
}

// R18: R13 skeleton + register shape (a[2][4], b[2][4], VGPR 72, no spill)
// with the dedup'd 6-load schedule. Clusters (Bplane, Aplane):
//   c0(p0,a0) c1(p0,a2) c2(p0,a4) c3(p1,a1) c4(p1,a3) c5(p1,a5)
//   c6(p2,a0) c7(p3,a1) c8(p4,a0) c9(p5,a1)
// b ping-pong: b0={p0 c0-2, p2 c6, p4 c8}, b1={p1 c3-5, p3 c7, p5 c9};
// reloads after last use: c2->b0<-p2 (use c6, dist 3), c5->b1<-p3 (c7, 2),
// c6->b0<-p4 (c8, 2), c7->b1<-p5 (c9, 2). Per-ci preload b0<-p0,b1<-p1
// (one exposed L2 latency x4/block ~5%, TLP-covered at 3 blocks/CU).
// a ping-pong prefetch-next as R13 (prefetch BEFORE MFMAs).
__global__ __launch_bounds__(256, 3) void vq_main(const float* __restrict__ x,
                                                  const ushortT* __restrict__ Bg,
                                                  const float* __restrict__ h2,
                                                  const float* __restrict__ emb,
                                                  float* __restrict__ out) {
  __shared__ ushortT A_lds[NPL * ASTEP];  // 24 KB  [plane][quad][row][8]
  __shared__ float bvs[4][MT];
  __shared__ int bis[4][MT];
  __shared__ int widx_s[MT];

  const int tid = threadIdx.x;
  const int wave = tid >> 6, lane = tid & 63, quad = lane >> 4, lq = lane & 15;
  const size_t rowbase = (size_t)blockIdx.x * MT;

  const ushortT* bci = Bg + ((size_t)(quad * KCODES + wave * 64 + lq)) * 8;
  const ushortT* ab = &A_lds[quad * (MT * 8) + lq * 8];

  // ---- stage A: x rows -> bf16 planes, frag-major, dedup'd (6 planes) ----
  {
    const int row = tid >> 2, dg = (tid & 3) << 4;
    const float4* xr = (const float4*)(x + (rowbase + row) * DIM + dg);
    float v[16];
#pragma unroll
    for (int i = 0; i < 4; ++i) {
      float4 t = xr[i];
      v[4 * i] = t.x; v[4 * i + 1] = t.y; v[4 * i + 2] = t.z; v[4 * i + 3] = t.w;
    }
    ushortT pl[3][16];
#pragma unroll
    for (int i = 0; i < 16; ++i) {
      ushortT a0 = f2bf(v[i]); float r1 = v[i] - bf2f(a0);
      ushortT a1 = f2bf(r1);   float r2 = r1 - bf2f(a1);
      pl[0][i] = a0; pl[1][i] = a1; pl[2][i] = f2bf(r2);
    }
    const int q0 = (dg & 31) >> 3;         // 0 or 2
    const int dh = dg >> 5;                // d-half
#pragma unroll
    for (int xp = 0; xp < 3; ++xp) {
      int pa = xp * 2 + dh;
      *(uint4*)&A_lds[pa * ASTEP + q0 * (MT * 8) + row * 8]       = *(uint4*)&pl[xp][0];
      *(uint4*)&A_lds[pa * ASTEP + (q0 + 1) * (MT * 8) + row * 8] = *(uint4*)&pl[xp][8];
    }
  }
  __syncthreads();  // A_lds ready; only block-wide barrier before epilogue

  float bestv[4][4];
  int besti[4][4];
#pragma unroll
  for (int i = 0; i < 4; ++i)
#pragma unroll
    for (int r = 0; r < 4; ++r) { bestv[i][r] = 3.4e38f; besti[i][r] = 0; }

// PRE_A(PN, AP): prefetch A plane AP into a[PN] (before MFMAs, R13 pattern).
// MFMA(AP, BS): 16 mfma on a[AP] x b[BS].
// RL_B(BS, BP): reload b[BS] <- B plane BP (after last use of old contents).
// All args literal -> compile-time indexing only.
#define PRE_A(PN, AP)                                                          \
  _Pragma("unroll")                                                            \
  for (int i = 0; i < 4; ++i)                                                  \
    a[PN][i] = *(const bf16x8*)(ab + (size_t)(AP) * ASTEP + i * 128);
#define MFMA(AP, BS)                                                           \
  _Pragma("unroll")                                                            \
  for (int i = 0; i < 4; ++i)                                                  \
    _Pragma("unroll")                                                          \
    for (int j = 0; j < 4; ++j)                                                \
      acc[i][j] = __builtin_amdgcn_mfma_f32_16x16x32_bf16(a[AP][i], b[BS][j],  \
                                                          acc[i][j], 0, 0, 0);
#define RL_B(BS, BP)                                                           \
  _Pragma("unroll")                                                            \
  for (int j = 0; j < 4; ++j)                                                  \
    b[BS][j] = *(const bf16x8*)(bcur + (size_t)(BP) * KCSTEP + j * 128);

#pragma unroll 1
  for (int ci = 0; ci < CI; ++ci) {
    const int codeBase = ci * NTC;
    const ushortT* bcur = bci + (size_t)codeBase * 8;

    bf16x8 a[2][4], b[2][4];
    RL_B(0, 0)                    // b0 <- p0 (e0d0)
    RL_B(1, 1)                    // b1 <- p1 (e0d1)
    PRE_A(0, 0)                   // a0 <- plane a0 (x0d0)

    f32x4 acc[4][4];
#pragma unroll
    for (int i = 0; i < 4; ++i)
#pragma unroll
      for (int j = 0; j < 4; ++j) acc[i][j] = (f32x4){0.f, 0.f, 0.f, 0.f};

    PRE_A(1, 2) MFMA(0, 0)              // c0: a0 x p0        ; pre a<-a2
    PRE_A(0, 4) MFMA(1, 0)              // c1: a2 x p0        ; pre a<-a4
    PRE_A(1, 1) MFMA(0, 0) RL_B(0, 2)   // c2: a4 x p0        ; pre a<-a1; b0<-p2
    PRE_A(0, 3) MFMA(1, 1)              // c3: a1 x p1        ; pre a<-a3
    PRE_A(1, 5) MFMA(0, 1)              // c4: a3 x p1        ; pre a<-a5
    PRE_A(0, 0) MFMA(1, 1) RL_B(1, 3)   // c5: a5 x p1        ; pre a<-a0; b1<-p3
    PRE_A(1, 1) MFMA(0, 0) RL_B(0, 4)   // c6: a0 x p2        ; pre a<-a1; b0<-p4
    PRE_A(0, 0) MFMA(1, 1) RL_B(1, 5)   // c7: a1 x p3        ; pre a<-a0; b1<-p5
    PRE_A(1, 1) MFMA(0, 0)              // c8: a0 x p4        ; pre a<-a1
    MFMA(1, 1)                          // c9: a1 x p5

    // epilogue: val = 0.5||e||^2 - f.e ; merge into per-row running best
    float h2v[4];
#pragma unroll
    for (int j = 0; j < 4; ++j) h2v[j] = h2[codeBase + wave * 64 + j * 16 + lq];
#pragma unroll
    for (int i = 0; i < 4; ++i)
#pragma unroll
      for (int j = 0; j < 4; ++j) {
        const int idx = codeBase + wave * 64 + j * 16 + lq;
#pragma unroll
        for (int r = 0; r < 4; ++r) {
          float val = h2v[j] - acc[i][j][r];
          if (val < bestv[i][r]) { bestv[i][r] = val; besti[i][r] = idx; }  // idx ascending in (ci,j): strict < keeps lowest
        }
      }
  }
#undef PRE_A
#undef MFMA
#undef RL_B

  // reduce across the 16 lanes sharing a quad (lane bits 0-3), lexicographic (val, idx)
#pragma unroll
  for (int m = 1; m < 16; m <<= 1) {
#pragma unroll
    for (int i = 0; i < 4; ++i)
#pragma unroll
      for (int r = 0; r < 4; ++r) {
        float ov = __shfl_xor(bestv[i][r], m, 64);
        int oi = __shfl_xor(besti[i][r], m, 64);
        if (ov < bestv[i][r] || (ov == bestv[i][r] && oi < besti[i][r])) {
          bestv[i][r] = ov; besti[i][r] = oi;
        }
      }
  }
  if (lq == 0) {
#pragma unroll
    for (int i = 0; i < 4; ++i)
#pragma unroll
      for (int r = 0; r < 4; ++r) {
        int row = i * 16 + quad * 4 + r;
        bvs[wave][row] = bestv[i][r];
        bis[wave][row] = besti[i][r];
      }
  }
  __syncthreads();
  if (tid < MT) {
    float bv = bvs[0][tid]; int bi = bis[0][tid];
#pragma unroll
    for (int w = 1; w < 4; ++w) {
      float ov = bvs[w][tid]; int oi = bis[w][tid];
      if (ov < bv || (ov == bv && oi < bi)) { bv = ov; bi = oi; }
    }
    widx_s[tid] = bi;
  }
  __syncthreads();
  // cooperative gather: thread handles row=tid>>2, 16 d's; emb is L2-resident (256KB)
  {
    const int row = tid >> 2, dg = (tid & 3) << 4;
    const int wi = widx_s[row];
    float4* o = (float4*)(out + (rowbase + row) * DIM + dg);
#pragma unroll
    for (int i = 0; i < 4; ++i) {
      float4 t;
      t.x = emb[(dg + 4 * i + 0) * KCODES + wi];
      t.y = emb[(dg + 4 * i + 1) * KCODES + wi];
      t.z = emb[(dg + 4 * i + 2) * KCODES + wi];
      t.w = emb[(dg + 4 * i + 3) * KCODES + wi];
      o[i] = t;
    }
  }
}

extern "C" void kernel_launch(void* const* d_in, const int* in_sizes, int n_in,
                              void* d_out, int out_size, void* d_ws, size_t ws_size,
                              hipStream_t stream) {
  const float* x = (const float*)d_in[0];
  const float* emb = (const float*)d_in[1];
  float* out = (float*)d_out;

  ushortT* Bg = (ushortT*)d_ws;               // 6*32768 ushort = 384 KB
  float* h2 = (float*)(Bg + NPL * (size_t)KCSTEP);  // 4 KB

  vq_prep<<<(NPL * KCSTEP) / (4 * 256), 256, 0, stream>>>(emb, Bg, h2);
  vq_main<<<NROWS / MT, 256, 0, stream>>>(x, Bg, h2, emb, out);
}

// Round 6
// 193.105 us; speedup vs baseline: 1.5318x; 1.5240x over previous
//
#include <hip/hip_runtime.h>
#include <stdint.h>

typedef unsigned short ushortT;

#define NROWS 131072
#define DIM 64
#define KCODES 1024
// 5 segments (xplane,eplane) = (0,0),(0,1),(0,2),(1,0),(2,0); x1e1 dropped (~4e-6).
// 6 DISTINCT planes each side: A = {x0d0,x0d1,x1d0,x1d1,x2d0,x2d1},
// B = {e0d0,e0d1,e1d0,e1d1,e2d0,e2d1}.
// R19 SPILL LESSON (R16/R17/R18 all ~360B/thread scratch, WRITE 217MB): a
// STRAIGHT-LINE 10-cluster ci body lets the scheduler hoist every B/A load
// above the MFMAs -> 200+ live VGPRs -> forced scratch, independent of ring
// depth (ring-5/ring-3/ring-2 all identical spill). R13 (clean, 121us) kept
// the cluster sequence inside a real `#pragma unroll 1` loop with a
// 2-cluster body. Fix: dedup'd schedule as 5 loop iterations of 2 clusters:
//   g0: e0 x x0   (B p0,p1 ; A 0,1)
//   g1: e0 x x1   (B p0,p1 ; A 2,3)
//   g2: e0 x x2   (B p0,p1 ; A 4,5)   reload b0<-p2, b1<-p3 (after use)
//   g3: e1 x x0   (B p2,p3 ; A 0,1)   reload b0<-p4, b1<-p5
//   g4: e2 x x0   (B p4,p5 ; A 0,1)
// -> 6 B plane-loads/ci (R13: 12 incl. waste), b ping-pong untouched g0-g2.
// Plane indices via uniform selects (no tables -> no rule-#20 scratch).
#define NPL 6               // distinct planes per side
#define MT 64               // rows per block (256 threads, 4 waves)
#define NTC 256             // codes per code-iter (4 waves x 64)
#define CI (KCODES / NTC)   // 4 code iters
#define KCSTEP (4 * KCODES * 8)  // ushort per B plane = 32768 (64KB)
#define ASTEP (4 * MT * 8)       // ushort per A plane = 2048 (4KB)

typedef float f32x4 __attribute__((ext_vector_type(4)));
typedef short bf16x8 __attribute__((ext_vector_type(8)));

__device__ __forceinline__ ushortT f2bf(float f) {
  union { float f; uint32_t u; } v; v.f = f;
  return (ushortT)((v.u + 0x7FFFu + ((v.u >> 16) & 1u)) >> 16);  // RNE
}
__device__ __forceinline__ float bf2f(ushortT b) {
  union { float f; uint32_t u; } v; v.u = ((uint32_t)b) << 16;
  return v.f;
}

// Output-major prep (verified R3/R4/R5): flat o = p*32768 + q*8192 + code*8+j;
// thread does 4 consecutive o (one uint2 store, coalesced). plane p: e-level
// ep = p>>1, d-half = p&1. h2[code] = 0.5*||e||^2 fp32 by blocks 0..3.
__global__ __launch_bounds__(256) void vq_prep(const float* __restrict__ emb,
                                               ushortT* __restrict__ Bg,
                                               float* __restrict__ h2) {
  const int o4 = (blockIdx.x * 256 + threadIdx.x) * 4;
  const int j0 = o4 & 7;                  // 0 or 4
  const int code = (o4 >> 3) & (KCODES - 1);
  const int q = (o4 >> 13) & 3;
  const int p = o4 >> 15;                 // 0..5 (block-uniform)
  const int ep = p >> 1;
  const int d0 = (p & 1) * 32 + q * 8 + j0;

  ushortT outv[4];
#pragma unroll
  for (int t = 0; t < 4; ++t) {
    float e = emb[(d0 + t) * KCODES + code];
    ushortT p0 = f2bf(e);
    ushortT pv = p0;
    if (ep == 1) {
      float r1 = e - bf2f(p0);            // exact (Sterbenz)
      pv = f2bf(r1);
    } else if (ep == 2) {
      float r1 = e - bf2f(p0);
      ushortT p1 = f2bf(r1);
      float r2 = r1 - bf2f(p1);           // exact
      pv = f2bf(r2);
    }
    outv[t] = pv;
  }
  *(uint2*)(&Bg[o4]) = *(const uint2*)(&outv[0]);

  if (blockIdx.x < 4) {
    const int c2 = blockIdx.x * 256 + threadIdx.x;
    float s = 0.f;
#pragma unroll
    for (int d = 0; d < DIM; ++d) {
      float e = emb[d * KCODES + c2];
      s = fmaf(e, e, s);
    }
    h2[c2] = 0.5f * s;
  }
}

// R19: R13 skeleton + loop shape (2 clusters per `#pragma unroll 1` iter,
// a[2][4]+b[2][4], prefetch-before-MFMA) with the 6-load dedup schedule.
__global__ __launch_bounds__(256, 3) void vq_main(const float* __restrict__ x,
                                                  const ushortT* __restrict__ Bg,
                                                  const float* __restrict__ h2,
                                                  const float* __restrict__ emb,
                                                  float* __restrict__ out) {
  __shared__ ushortT A_lds[NPL * ASTEP];  // 24 KB  [plane][quad][row][8]
  __shared__ float bvs[4][MT];
  __shared__ int bis[4][MT];
  __shared__ int widx_s[MT];

  const int tid = threadIdx.x;
  const int wave = tid >> 6, lane = tid & 63, quad = lane >> 4, lq = lane & 15;
  const size_t rowbase = (size_t)blockIdx.x * MT;

  const ushortT* bci = Bg + ((size_t)(quad * KCODES + wave * 64 + lq)) * 8;
  const ushortT* ab = &A_lds[quad * (MT * 8) + lq * 8];

  // ---- stage A: x rows -> bf16 planes, frag-major, dedup'd (6 planes) ----
  {
    const int row = tid >> 2, dg = (tid & 3) << 4;
    const float4* xr = (const float4*)(x + (rowbase + row) * DIM + dg);
    float v[16];
#pragma unroll
    for (int i = 0; i < 4; ++i) {
      float4 t = xr[i];
      v[4 * i] = t.x; v[4 * i + 1] = t.y; v[4 * i + 2] = t.z; v[4 * i + 3] = t.w;
    }
    ushortT pl[3][16];
#pragma unroll
    for (int i = 0; i < 16; ++i) {
      ushortT a0 = f2bf(v[i]); float r1 = v[i] - bf2f(a0);
      ushortT a1 = f2bf(r1);   float r2 = r1 - bf2f(a1);
      pl[0][i] = a0; pl[1][i] = a1; pl[2][i] = f2bf(r2);
    }
    const int q0 = (dg & 31) >> 3;         // 0 or 2
    const int dh = dg >> 5;                // d-half
#pragma unroll
    for (int xp = 0; xp < 3; ++xp) {
      int pa = xp * 2 + dh;
      *(uint4*)&A_lds[pa * ASTEP + q0 * (MT * 8) + row * 8]       = *(uint4*)&pl[xp][0];
      *(uint4*)&A_lds[pa * ASTEP + (q0 + 1) * (MT * 8) + row * 8] = *(uint4*)&pl[xp][8];
    }
  }
  __syncthreads();  // A_lds ready; only block-wide barrier before epilogue

  float bestv[4][4];
  int besti[4][4];
#pragma unroll
  for (int i = 0; i < 4; ++i)
#pragma unroll
    for (int r = 0; r < 4; ++r) { bestv[i][r] = 3.4e38f; besti[i][r] = 0; }

#pragma unroll 1
  for (int ci = 0; ci < CI; ++ci) {
    const int codeBase = ci * NTC;
    const ushortT* bcur = bci + (size_t)codeBase * 8;

    bf16x8 a[2][4], b[2][4];
    // preload: b0<-p0 (e0d0), b1<-p1 (e0d1), a[0]<-A plane 0 (x0d0)
#pragma unroll
    for (int j = 0; j < 4; ++j) b[0][j] = *(const bf16x8*)(bcur + j * 128);
#pragma unroll
    for (int j = 0; j < 4; ++j) b[1][j] = *(const bf16x8*)(bcur + KCSTEP + j * 128);
#pragma unroll
    for (int i = 0; i < 4; ++i) a[0][i] = *(const bf16x8*)(ab + i * 128);

    f32x4 acc[4][4];
#pragma unroll
    for (int i = 0; i < 4; ++i)
#pragma unroll
      for (int j = 0; j < 4; ++j) acc[i][j] = (f32x4){0.f, 0.f, 0.f, 0.f};

#pragma unroll 1
    for (int g = 0; g < 5; ++g) {
      // A planes: cluster 2g uses pA0[g]={0,2,4,0,0}, 2g+1 uses pA1[g]={1,3,5,1,1}
      const int pa1 = (g < 3) ? (2 * g + 1) : 1;   // prefetched for t1
      const int pa0n = (g < 2) ? (2 * g + 2) : 0;  // prefetched for next g's t0
      // --- t0 (cluster 2g): prefetch a[1] BEFORE MFMAs (R13 pattern) ---
#pragma unroll
      for (int i = 0; i < 4; ++i)
        a[1][i] = *(const bf16x8*)(ab + (size_t)pa1 * ASTEP + i * 128);
#pragma unroll
      for (int i = 0; i < 4; ++i)
#pragma unroll
        for (int j = 0; j < 4; ++j)
          acc[i][j] = __builtin_amdgcn_mfma_f32_16x16x32_bf16(a[0][i], b[0][j], acc[i][j], 0, 0, 0);
      if (g == 2 || g == 3) {  // uniform branch; reload after last use
        const size_t pb0 = (g == 2) ? 2 : 4;
#pragma unroll
        for (int j = 0; j < 4; ++j)
          b[0][j] = *(const bf16x8*)(bcur + pb0 * KCSTEP + j * 128);
      }
      // --- t1 (cluster 2g+1): prefetch a[0] for next g BEFORE MFMAs ---
#pragma unroll
      for (int i = 0; i < 4; ++i)
        a[0][i] = *(const bf16x8*)(ab + (size_t)pa0n * ASTEP + i * 128);
#pragma unroll
      for (int i = 0; i < 4; ++i)
#pragma unroll
        for (int j = 0; j < 4; ++j)
          acc[i][j] = __builtin_amdgcn_mfma_f32_16x16x32_bf16(a[1][i], b[1][j], acc[i][j], 0, 0, 0);
      if (g == 2 || g == 3) {
        const size_t pb1 = (g == 2) ? 3 : 5;
#pragma unroll
        for (int j = 0; j < 4; ++j)
          b[1][j] = *(const bf16x8*)(bcur + pb1 * KCSTEP + j * 128);
      }
    }

    // epilogue: val = 0.5||e||^2 - f.e ; merge into per-row running best
    float h2v[4];
#pragma unroll
    for (int j = 0; j < 4; ++j) h2v[j] = h2[codeBase + wave * 64 + j * 16 + lq];
#pragma unroll
    for (int i = 0; i < 4; ++i)
#pragma unroll
      for (int j = 0; j < 4; ++j) {
        const int idx = codeBase + wave * 64 + j * 16 + lq;
#pragma unroll
        for (int r = 0; r < 4; ++r) {
          float val = h2v[j] - acc[i][j][r];
          if (val < bestv[i][r]) { bestv[i][r] = val; besti[i][r] = idx; }  // idx ascending in (ci,j): strict < keeps lowest
        }
      }
  }

  // reduce across the 16 lanes sharing a quad (lane bits 0-3), lexicographic (val, idx)
#pragma unroll
  for (int m = 1; m < 16; m <<= 1) {
#pragma unroll
    for (int i = 0; i < 4; ++i)
#pragma unroll
      for (int r = 0; r < 4; ++r) {
        float ov = __shfl_xor(bestv[i][r], m, 64);
        int oi = __shfl_xor(besti[i][r], m, 64);
        if (ov < bestv[i][r] || (ov == bestv[i][r] && oi < besti[i][r])) {
          bestv[i][r] = ov; besti[i][r] = oi;
        }
      }
  }
  if (lq == 0) {
#pragma unroll
    for (int i = 0; i < 4; ++i)
#pragma unroll
      for (int r = 0; r < 4; ++r) {
        int row = i * 16 + quad * 4 + r;
        bvs[wave][row] = bestv[i][r];
        bis[wave][row] = besti[i][r];
      }
  }
  __syncthreads();
  if (tid < MT) {
    float bv = bvs[0][tid]; int bi = bis[0][tid];
#pragma unroll
    for (int w = 1; w < 4; ++w) {
      float ov = bvs[w][tid]; int oi = bis[w][tid];
      if (ov < bv || (ov == bv && oi < bi)) { bv = ov; bi = oi; }
    }
    widx_s[tid] = bi;
  }
  __syncthreads();
  // cooperative gather: thread handles row=tid>>2, 16 d's; emb is L2-resident (256KB)
  {
    const int row = tid >> 2, dg = (tid & 3) << 4;
    const int wi = widx_s[row];
    float4* o = (float4*)(out + (rowbase + row) * DIM + dg);
#pragma unroll
    for (int i = 0; i < 4; ++i) {
      float4 t;
      t.x = emb[(dg + 4 * i + 0) * KCODES + wi];
      t.y = emb[(dg + 4 * i + 1) * KCODES + wi];
      t.z = emb[(dg + 4 * i + 2) * KCODES + wi];
      t.w = emb[(dg + 4 * i + 3) * KCODES + wi];
      o[i] = t;
    }
  }
}

extern "C" void kernel_launch(void* const* d_in, const int* in_sizes, int n_in,
                              void* d_out, int out_size, void* d_ws, size_t ws_size,
                              hipStream_t stream) {
  const float* x = (const float*)d_in[0];
  const float* emb = (const float*)d_in[1];
  float* out = (float*)d_out;

  ushortT* Bg = (ushortT*)d_ws;               // 6*32768 ushort = 384 KB
  float* h2 = (float*)(Bg + NPL * (size_t)KCSTEP);  // 4 KB

  vq_prep<<<(NPL * KCSTEP) / (4 * 256), 256, 0, stream>>>(emb, Bg, h2);
  vq_main<<<NROWS / MT, 256, 0, stream>>>(x, Bg, h2, emb, out);
}